// Round 10
// baseline (819.948 us; speedup 1.0000x reference)
//
#include <hip/hip_runtime.h>
#include <hip/hip_bf16.h>

// Problem constants fixed by setup_inputs()
#define NNODE   20000
#define BS      8
#define NEG1    33
#define DDIM    32
#define NLAYER  6
#define NRELX2  128     // 2*N_REL
#define FEAT    256     // BS*DDIM
#define INW     416     // 13*DDIM
#define NPB     10      // nodes per block, ONE group -> grid 2000

// ---------------------------------------------------------------- precompute
__global__ void count_kernel(const int* __restrict__ es, const int* __restrict__ ed,
                             int* __restrict__ cnt, int E) {
    int i = blockIdx.x * 256 + threadIdx.x;
    if (i >= 2 * E) return;
    int dst = (i < E) ? ed[i] : es[i - E];
    atomicAdd(&cnt[dst], 1);
}

__global__ void scan_kernel(const int* __restrict__ cnt, int* __restrict__ row_ptr, int N) {
    __shared__ int sh[1024];
    __shared__ int s_carry;
    if (threadIdx.x == 0) { s_carry = 0; row_ptr[0] = 0; }
    __syncthreads();
    for (int base = 0; base < N; base += 1024) {
        int i = base + threadIdx.x;
        int v = (i < N) ? cnt[i] : 0;
        sh[threadIdx.x] = v;
        __syncthreads();
        for (int off = 1; off < 1024; off <<= 1) {
            int t = (threadIdx.x >= off) ? sh[threadIdx.x - off] : 0;
            __syncthreads();
            sh[threadIdx.x] += t;
            __syncthreads();
        }
        int carry = s_carry;
        if (i < N) row_ptr[i + 1] = carry + sh[threadIdx.x];
        __syncthreads();
        if (threadIdx.x == 1023) s_carry = carry + sh[1023];
        __syncthreads();
    }
}

// csr_pack = (src << 16) | etype   (src < 20000 < 65536, etype < 128)
__global__ void fill_kernel(const int* __restrict__ es, const int* __restrict__ ed,
                            const int* __restrict__ et, const int* __restrict__ row_ptr,
                            int* __restrict__ cursor, int* __restrict__ csr_pack, int E) {
    int i = blockIdx.x * 256 + threadIdx.x;
    if (i >= 2 * E) return;
    int src, dst, ty;
    if (i < E) { src = es[i]; dst = ed[i]; ty = et[i]; }
    else       { src = ed[i - E]; dst = es[i - E]; ty = et[i - E] + 64; }
    int pos = row_ptr[dst] + atomicAdd(&cursor[dst], 1);
    csr_pack[pos] = (src << 16) | ty;
}

__global__ void deg_kernel(const int* __restrict__ cnt, float* __restrict__ dinv,
                           float* __restrict__ logdeg, int N) {
    int n = blockIdx.x * 256 + threadIdx.x;
    if (n >= N) return;
    float deg = (float)cnt[n] + 1.0f;
    dinv[n] = 1.0f / deg;
    logdeg[n] = logf(deg);
}

__global__ void mean_kernel(const float* __restrict__ logdeg, float* __restrict__ meanout, int N) {
    __shared__ float sh[256];
    float s = 0.f;
    for (int i = threadIdx.x; i < N; i += 256) s += logdeg[i];
    sh[threadIdx.x] = s;
    __syncthreads();
    for (int off = 128; off > 0; off >>= 1) {
        if (threadIdx.x < off) sh[threadIdx.x] += sh[threadIdx.x + off];
        __syncthreads();
    }
    if (threadIdx.x == 0) meanout[0] = sh[0] / (float)N;
}

__global__ void sc_kernel(const float* __restrict__ logdeg, const float* __restrict__ meanp,
                          float* __restrict__ sc, int N) {
    int n = blockIdx.x * 256 + threadIdx.x;
    if (n >= N) return;
    sc[n] = logdeg[n] / meanp[0];
}

__global__ void prep_kernel(const int* __restrict__ h_index, const int* __restrict__ t_index,
                            const int* __restrict__ r_index, const float* __restrict__ rel_query,
                            int* __restrict__ h0, int* __restrict__ r0,
                            float* __restrict__ query, int* __restrict__ tnew) {
    __shared__ int s_isneg[BS];
    __shared__ int s_r0[BS];
    int t = threadIdx.x;
    if (t < BS) {
        int b = t;
        int hv = h_index[b * NEG1];
        int all = 1;
        for (int j = 1; j < NEG1; j++) all &= (h_index[b * NEG1 + j] == hv);
        s_isneg[b] = all;
        int h0v = all ? hv : t_index[b * NEG1];
        int r0v = all ? r_index[b * NEG1] : r_index[b * NEG1] + 64;
        s_r0[b] = r0v;
        h0[b] = h0v;
        r0[b] = r0v;
    }
    __syncthreads();
    {
        int b = t >> 5, dd = t & 31;
        query[t] = rel_query[s_r0[b] * DDIM + dd];
    }
    for (int idx = t; idx < BS * NEG1; idx += 256) {
        int b = idx / NEG1;
        tnew[idx] = s_isneg[b] ? t_index[idx] : h_index[idx];
    }
}

__global__ void rel_kernel(const float* __restrict__ rel_query, const float* __restrict__ Wrel,
                           const float* __restrict__ brel, float* __restrict__ rel_all) {
    int idx = blockIdx.x * 256 + threadIdx.x;
    if (idx >= NLAYER * NRELX2 * DDIM) return;
    int i  = idx >> 12;          // / 4096
    int q  = (idx >> 5) & 127;
    int dd = idx & 31;
    float acc = brel[i * DDIM + dd];
    #pragma unroll
    for (int k = 0; k < DDIM; k++)
        acc = fmaf(rel_query[q * DDIM + k], Wrel[i * DDIM * DDIM + k * DDIM + dd], acc);
    rel_all[idx] = acc;
}

// Wg[layer][step][j][dd] = Wlin[layer][k_j(dd)][(dd+step)&31]
__global__ void wg_kernel(const float* __restrict__ Wlin, float* __restrict__ wg) {
    int idx = blockIdx.x * 256 + threadIdx.x;       // NLAYER*32*13*32
    if (idx >= NLAYER * 32 * 13 * 32) return;
    int dd = idx & 31;
    int r  = idx >> 5;
    int j  = r % 13;
    int r2 = r / 13;
    int step  = r2 & 31;
    int layer = r2 >> 5;
    int k;
    if (j == 0) k = dd;
    else { int s = (j - 1) / 3, scl = (j - 1) % 3; k = 32 + (dd * 4 + s) * 3 + scl; }
    int col = (dd + step) & 31;
    wg[idx] = Wlin[(layer * INW + k) * DDIM + col];
}

__global__ void init_x_kernel(float* __restrict__ x, const int* __restrict__ h0,
                              const float* __restrict__ query) {
    int i = blockIdx.x * 256 + threadIdx.x;
    if (i >= NNODE * FEAT) return;
    int n = i >> 8;
    int t = i & 255;
    int b = t >> 5;
    x[i] = (h0[b] == n) ? query[t] : 0.f;
}

// ---------------------------------------------------------------- main layer
// Per block: 10 nodes, ONE group. 13 PRE-SCALED stats per node (GSTEP = pure
// 13-FMA chain, no recombination temps). Weights step-contiguous, loaded once
// per block per step; systolic accumulator rotation.

#define STATS_COMP(U, NODE) {                                                 \
    int n_ = (NODE);                                                          \
    float bv_ = (h0b == n_) ? q : 0.f;                                        \
    float sum_ = bv_, ssq_ = bv_ * bv_, vmx_ = bv_, vmn_ = bv_;               \
    int e0_ = row_ptr[n_], e1_ = row_ptr[n_ + 1];                             \
    ps0##U = x_in[n_ * FEAT + t];                                             \
    int e_ = e0_;                                                             \
    for (; e_ + 3 < e1_; e_ += 4) {                                           \
        int pa_ = csr_pack[e_];                                               \
        int pb_ = csr_pack[e_ + 1];                                           \
        int pc_ = csr_pack[e_ + 2];                                           \
        int pd_ = csr_pack[e_ + 3];                                           \
        float xa_ = x_in[(pa_ >> 16) * FEAT + t];                             \
        float xb_ = x_in[(pb_ >> 16) * FEAT + t];                             \
        float xc_ = x_in[(pc_ >> 16) * FEAT + t];                             \
        float xd_ = x_in[(pd_ >> 16) * FEAT + t];                             \
        float ra_ = s_rel[((pa_ & 0xFFFF) << 5) + dd];                        \
        float rb_ = s_rel[((pb_ & 0xFFFF) << 5) + dd];                        \
        float rc_ = s_rel[((pc_ & 0xFFFF) << 5) + dd];                        \
        float rd_ = s_rel[((pd_ & 0xFFFF) << 5) + dd];                        \
        float ma_ = xa_ * ra_, mb_ = xb_ * rb_;                               \
        float mc_ = xc_ * rc_, md_ = xd_ * rd_;                               \
        sum_ += ((ma_ + mb_) + (mc_ + md_));                                  \
        ssq_ = fmaf(ma_, ma_, ssq_); ssq_ = fmaf(mb_, mb_, ssq_);             \
        ssq_ = fmaf(mc_, mc_, ssq_); ssq_ = fmaf(md_, md_, ssq_);             \
        vmx_ = fmaxf(vmx_, fmaxf(fmaxf(ma_, mb_), fmaxf(mc_, md_)));         \
        vmn_ = fminf(vmn_, fminf(fminf(ma_, mb_), fminf(mc_, md_)));         \
    }                                                                         \
    for (; e_ < e1_; ++e_) {                                                  \
        int p_  = csr_pack[e_];                                               \
        float m_ = x_in[(p_ >> 16) * FEAT + t]                                \
                   * s_rel[((p_ & 0xFFFF) << 5) + dd];                        \
        sum_ += m_; ssq_ = fmaf(m_, m_, ssq_);                                \
        vmx_ = fmaxf(vmx_, m_); vmn_ = fminf(vmn_, m_);                       \
    }                                                                         \
    float dv_ = dinv[n_];                                                     \
    float me_ = sum_ * dv_;                                                   \
    float sq_ = ssq_ * dv_;                                                   \
    float sd_ = sqrtf(fmaxf(sq_ - me_ * me_, 1e-6f));                         \
    float sv_ = sc[n_];                                                       \
    float s2_ = 1.0f / fmaxf(sv_, 0.01f);                                     \
    ps1##U  = me_;  ps2##U  = me_ * sv_;  ps3##U  = me_ * s2_;                \
    ps4##U  = vmx_; ps5##U  = vmx_ * sv_; ps6##U  = vmx_ * s2_;               \
    ps7##U  = vmn_; ps8##U  = vmn_ * sv_; ps9##U  = vmn_ * s2_;               \
    ps10##U = sd_;  ps11##U = sd_ * sv_;  ps12##U = sd_ * s2_;                \
}

#define SDECL(U) float ps0##U, ps1##U, ps2##U, ps3##U, ps4##U, ps5##U,        \
    ps6##U, ps7##U, ps8##U, ps9##U, ps10##U, ps11##U, ps12##U;

#define GSTEP(U) {                                                            \
    float a_ = acc##U;                                                        \
    a_ = fmaf(ps0##U,  w0,  a_);                                              \
    a_ = fmaf(ps1##U,  w1,  a_);                                              \
    a_ = fmaf(ps2##U,  w2,  a_);                                              \
    a_ = fmaf(ps3##U,  w3,  a_);                                              \
    a_ = fmaf(ps4##U,  w4,  a_);                                              \
    a_ = fmaf(ps5##U,  w5,  a_);                                              \
    a_ = fmaf(ps6##U,  w6,  a_);                                              \
    a_ = fmaf(ps7##U,  w7,  a_);                                              \
    a_ = fmaf(ps8##U,  w8,  a_);                                              \
    a_ = fmaf(ps9##U,  w9,  a_);                                              \
    a_ = fmaf(ps10##U, w10, a_);                                              \
    a_ = fmaf(ps11##U, w11, a_);                                              \
    a_ = fmaf(ps12##U, w12, a_);                                              \
    acc##U = a_;                                                              \
}

#define ROT(U) acc##U = __int_as_float(__builtin_amdgcn_ds_bpermute(          \
                            bperm_addr, __float_as_int(acc##U)));

#define LNSTORE(U, NODE) {                                                    \
    int n_ = (NODE);                                                          \
    float v_ = acc##U;                                                        \
    float s1_ = v_;                                                           \
    s1_ += __shfl_xor(s1_, 16, 32); s1_ += __shfl_xor(s1_, 8, 32);            \
    s1_ += __shfl_xor(s1_, 4, 32);  s1_ += __shfl_xor(s1_, 2, 32);            \
    s1_ += __shfl_xor(s1_, 1, 32);                                            \
    float lm_ = s1_ * (1.0f / 32.0f);                                         \
    float dl_ = v_ - lm_;                                                     \
    float p2_ = dl_ * dl_;                                                    \
    p2_ += __shfl_xor(p2_, 16, 32); p2_ += __shfl_xor(p2_, 8, 32);            \
    p2_ += __shfl_xor(p2_, 4, 32);  p2_ += __shfl_xor(p2_, 2, 32);            \
    p2_ += __shfl_xor(p2_, 1, 32);                                            \
    float var_ = p2_ * (1.0f / 32.0f);                                        \
    float y_ = dl_ / sqrtf(var_ + 1e-5f) * gdd + bdd;                         \
    y_ = fmaxf(y_, 0.0f);                                                     \
    x_out[n_ * FEAT + t] = y_ + ps0##U;                                       \
}

__global__ __launch_bounds__(256, 3) void layer_kernel(
    const float* __restrict__ x_in, float* __restrict__ x_out,
    const int* __restrict__ row_ptr, const int* __restrict__ csr_pack,
    const float* __restrict__ rel_i,     // [128][32]
    const float* __restrict__ wg_i,      // [32][13][32]
    const float* __restrict__ blin_i, const float* __restrict__ g_i,
    const float* __restrict__ b_i,
    const float* __restrict__ dinv, const float* __restrict__ sc,
    const int* __restrict__ h0, const float* __restrict__ query) {
    int t  = threadIdx.x;
    int b  = t >> 5, dd = t & 31;
    int lane = t & 63;
    __shared__ float s_rel[NRELX2 * DDIM];   // 16 KB

    for (int k = t; k < NRELX2 * DDIM; k += 256) s_rel[k] = rel_i[k];

    float q   = query[t];
    int   h0b = h0[b];
    float gdd = g_i[dd], bdd = b_i[dd], bl = blin_i[dd];
    // rotate-down-by-1 within each 32-lane half of the wave (pull from lane+1)
    int bperm_addr = ((((lane + 1) & 31) | (lane & 32)) << 2);
    __syncthreads();

    int nbase = blockIdx.x * NPB;
    SDECL(0) SDECL(1) SDECL(2) SDECL(3) SDECL(4)
    SDECL(5) SDECL(6) SDECL(7) SDECL(8) SDECL(9)
    STATS_COMP(0, nbase + 0)
    STATS_COMP(1, nbase + 1)
    STATS_COMP(2, nbase + 2)
    STATS_COMP(3, nbase + 3)
    STATS_COMP(4, nbase + 4)
    STATS_COMP(5, nbase + 5)
    STATS_COMP(6, nbase + 6)
    STATS_COMP(7, nbase + 7)
    STATS_COMP(8, nbase + 8)
    STATS_COMP(9, nbase + 9)

    float acc0 = bl, acc1 = bl, acc2 = bl, acc3 = bl, acc4 = bl;
    float acc5 = bl, acc6 = bl, acc7 = bl, acc8 = bl, acc9 = bl;

    #pragma unroll 1
    for (int i = 0; i < 32; ++i) {
        const float* wp = wg_i + i * 416 + dd;   // step-contiguous
        float w0  = wp[0 * 32],  w1  = wp[1 * 32],  w2  = wp[2 * 32];
        float w3  = wp[3 * 32],  w4  = wp[4 * 32],  w5  = wp[5 * 32];
        float w6  = wp[6 * 32],  w7  = wp[7 * 32],  w8  = wp[8 * 32];
        float w9  = wp[9 * 32],  w10 = wp[10 * 32], w11 = wp[11 * 32];
        float w12 = wp[12 * 32];
        GSTEP(0) GSTEP(1) GSTEP(2) GSTEP(3) GSTEP(4)
        GSTEP(5) GSTEP(6) GSTEP(7) GSTEP(8) GSTEP(9)
        ROT(0) ROT(1) ROT(2) ROT(3) ROT(4)
        ROT(5) ROT(6) ROT(7) ROT(8) ROT(9)
    }
    // 32 rotations = identity: lane dd again holds col dd

    LNSTORE(0, nbase + 0)
    LNSTORE(1, nbase + 1)
    LNSTORE(2, nbase + 2)
    LNSTORE(3, nbase + 3)
    LNSTORE(4, nbase + 4)
    LNSTORE(5, nbase + 5)
    LNSTORE(6, nbase + 6)
    LNSTORE(7, nbase + 7)
    LNSTORE(8, nbase + 8)
    LNSTORE(9, nbase + 9)
}

// ---------------------------------------------------------------- readout
__global__ void score_kernel(const float* __restrict__ x, const int* __restrict__ tnew,
                             const float* __restrict__ query,
                             const float* __restrict__ W1, const float* __restrict__ b1,
                             const float* __restrict__ W2, const float* __restrict__ b2,
                             float* __restrict__ out) {
    int idx = blockIdx.x;         // b*33+j
    int b = idx / NEG1;
    int k = threadIdx.x;          // 0..63
    __shared__ float v[64];
    int tnode = tnew[idx];
    if (k < 32) v[k] = x[tnode * FEAT + b * DDIM + k];
    else        v[k] = query[b * DDIM + (k - 32)];
    __syncthreads();
    float acc = b1[k];
    #pragma unroll
    for (int l = 0; l < 64; l++) acc = fmaf(v[l], W1[l * 64 + k], acc);
    acc = fmaxf(acc, 0.f);
    float p = acc * W2[k];
    #pragma unroll
    for (int m = 32; m >= 1; m >>= 1) p += __shfl_xor(p, m);
    if (k == 0) out[idx] = p + b2[0];
}

// ---------------------------------------------------------------- launch
extern "C" void kernel_launch(void* const* d_in, const int* in_sizes, int n_in,
                              void* d_out, int out_size, void* d_ws, size_t ws_size,
                              hipStream_t stream) {
    const int* edge_src  = (const int*)d_in[0];
    const int* edge_dst  = (const int*)d_in[1];
    const int* edge_type = (const int*)d_in[2];
    const int* h_index   = (const int*)d_in[3];
    const int* t_index   = (const int*)d_in[4];
    const int* r_index   = (const int*)d_in[5];
    const float* rel_query = (const float*)d_in[7];
    const float* Wrel    = (const float*)d_in[8];
    const float* brel    = (const float*)d_in[9];
    const float* Wlin    = (const float*)d_in[10];
    const float* blin    = (const float*)d_in[11];
    const float* ln_g    = (const float*)d_in[12];
    const float* ln_b    = (const float*)d_in[13];
    const float* W1      = (const float*)d_in[14];
    const float* b1      = (const float*)d_in[15];
    const float* W2      = (const float*)d_in[16];
    const float* b2      = (const float*)d_in[17];

    const int N  = NNODE;
    const int E  = in_sizes[0];
    const int E2 = 2 * E;

    char* p = (char*)d_ws;
    auto carve = [&](size_t bytes) {
        void* r = (void*)p;
        p += (bytes + 255) & ~(size_t)255;
        return r;
    };
    float* x0      = (float*)carve((size_t)N * FEAT * 4);
    float* x1      = (float*)carve((size_t)N * FEAT * 4);
    int*   cnt     = (int*)carve((size_t)N * 4);
    int*   row_ptr = (int*)carve((size_t)(N + 1) * 4);
    int*   cursor  = (int*)carve((size_t)N * 4);
    int*   csr_pack= (int*)carve((size_t)E2 * 4);
    float* dinv    = (float*)carve((size_t)N * 4);
    float* logdeg  = (float*)carve((size_t)N * 4);
    float* scn     = (float*)carve((size_t)N * 4);
    float* meanp   = (float*)carve(16);
    float* rel_all = (float*)carve((size_t)NLAYER * NRELX2 * DDIM * 4);
    float* wg      = (float*)carve((size_t)NLAYER * 32 * 13 * 32 * 4);
    int*   h0      = (int*)carve(BS * 4);
    int*   r0      = (int*)carve(BS * 4);
    float* query   = (float*)carve(BS * DDIM * 4);
    int*   tnew    = (int*)carve(BS * NEG1 * 4);

    hipMemsetAsync(cnt, 0, (size_t)N * 4, stream);
    hipMemsetAsync(cursor, 0, (size_t)N * 4, stream);

    int eb = (E2 + 255) / 256;
    count_kernel<<<eb, 256, 0, stream>>>(edge_src, edge_dst, cnt, E);
    scan_kernel<<<1, 1024, 0, stream>>>(cnt, row_ptr, N);
    fill_kernel<<<eb, 256, 0, stream>>>(edge_src, edge_dst, edge_type, row_ptr,
                                        cursor, csr_pack, E);
    deg_kernel<<<(N + 255) / 256, 256, 0, stream>>>(cnt, dinv, logdeg, N);
    mean_kernel<<<1, 256, 0, stream>>>(logdeg, meanp, N);
    sc_kernel<<<(N + 255) / 256, 256, 0, stream>>>(logdeg, meanp, scn, N);
    prep_kernel<<<1, 256, 0, stream>>>(h_index, t_index, r_index, rel_query,
                                       h0, r0, query, tnew);
    rel_kernel<<<(NLAYER * NRELX2 * DDIM + 255) / 256, 256, 0, stream>>>(
        rel_query, Wrel, brel, rel_all);
    wg_kernel<<<(NLAYER * 32 * 13 * 32 + 255) / 256, 256, 0, stream>>>(Wlin, wg);
    init_x_kernel<<<(N * FEAT + 255) / 256, 256, 0, stream>>>(x0, h0, query);

    float* xin = x0;
    float* xout = x1;
    for (int i = 0; i < NLAYER; ++i) {
        layer_kernel<<<N / NPB, 256, 0, stream>>>(
            xin, xout, row_ptr, csr_pack,
            rel_all + (size_t)i * NRELX2 * DDIM,
            wg + (size_t)i * 32 * 13 * 32,
            blin + (size_t)i * DDIM,
            ln_g + (size_t)i * DDIM,
            ln_b + (size_t)i * DDIM,
            dinv, scn, h0, query);
        float* tmp = xin; xin = xout; xout = tmp;
    }

    score_kernel<<<BS * NEG1, 64, 0, stream>>>(xin, tnew, query, W1, b1, W2, b2,
                                               (float*)d_out);
}

// Round 11
// 815.823 us; speedup vs baseline: 1.0051x; 1.0051x over previous
//
#include <hip/hip_runtime.h>
#include <hip/hip_bf16.h>

// Problem constants fixed by setup_inputs()
#define NNODE   20000
#define BS      8
#define NEG1    33
#define DDIM    32
#define NLAYER  6
#define NRELX2  128     // 2*N_REL
#define FEAT    256     // BS*DDIM
#define INW     416     // 13*DDIM
#define NPB     10      // nodes per block, ONE group -> grid 2000

// ---------------------------------------------------------------- precompute
__global__ void count_kernel(const int* __restrict__ es, const int* __restrict__ ed,
                             int* __restrict__ cnt, int E) {
    int i = blockIdx.x * 256 + threadIdx.x;
    if (i >= 2 * E) return;
    int dst = (i < E) ? ed[i] : es[i - E];
    atomicAdd(&cnt[dst], 1);
}

__global__ void scan_kernel(const int* __restrict__ cnt, int* __restrict__ row_ptr, int N) {
    __shared__ int sh[1024];
    __shared__ int s_carry;
    if (threadIdx.x == 0) { s_carry = 0; row_ptr[0] = 0; }
    __syncthreads();
    for (int base = 0; base < N; base += 1024) {
        int i = base + threadIdx.x;
        int v = (i < N) ? cnt[i] : 0;
        sh[threadIdx.x] = v;
        __syncthreads();
        for (int off = 1; off < 1024; off <<= 1) {
            int t = (threadIdx.x >= off) ? sh[threadIdx.x - off] : 0;
            __syncthreads();
            sh[threadIdx.x] += t;
            __syncthreads();
        }
        int carry = s_carry;
        if (i < N) row_ptr[i + 1] = carry + sh[threadIdx.x];
        __syncthreads();
        if (threadIdx.x == 1023) s_carry = carry + sh[1023];
        __syncthreads();
    }
}

// csr_pack = (src << 16) | etype   (src < 20000 < 65536, etype < 128)
__global__ void fill_kernel(const int* __restrict__ es, const int* __restrict__ ed,
                            const int* __restrict__ et, const int* __restrict__ row_ptr,
                            int* __restrict__ cursor, int* __restrict__ csr_pack, int E) {
    int i = blockIdx.x * 256 + threadIdx.x;
    if (i >= 2 * E) return;
    int src, dst, ty;
    if (i < E) { src = es[i]; dst = ed[i]; ty = et[i]; }
    else       { src = ed[i - E]; dst = es[i - E]; ty = et[i - E] + 64; }
    int pos = row_ptr[dst] + atomicAdd(&cursor[dst], 1);
    csr_pack[pos] = (src << 16) | ty;
}

__global__ void deg_kernel(const int* __restrict__ cnt, float* __restrict__ dinv,
                           float* __restrict__ logdeg, int N) {
    int n = blockIdx.x * 256 + threadIdx.x;
    if (n >= N) return;
    float deg = (float)cnt[n] + 1.0f;
    dinv[n] = 1.0f / deg;
    logdeg[n] = logf(deg);
}

__global__ void mean_kernel(const float* __restrict__ logdeg, float* __restrict__ meanout, int N) {
    __shared__ float sh[256];
    float s = 0.f;
    for (int i = threadIdx.x; i < N; i += 256) s += logdeg[i];
    sh[threadIdx.x] = s;
    __syncthreads();
    for (int off = 128; off > 0; off >>= 1) {
        if (threadIdx.x < off) sh[threadIdx.x] += sh[threadIdx.x + off];
        __syncthreads();
    }
    if (threadIdx.x == 0) meanout[0] = sh[0] / (float)N;
}

__global__ void sc_kernel(const float* __restrict__ logdeg, const float* __restrict__ meanp,
                          float* __restrict__ sc, int N) {
    int n = blockIdx.x * 256 + threadIdx.x;
    if (n >= N) return;
    sc[n] = logdeg[n] / meanp[0];
}

__global__ void prep_kernel(const int* __restrict__ h_index, const int* __restrict__ t_index,
                            const int* __restrict__ r_index, const float* __restrict__ rel_query,
                            int* __restrict__ h0, int* __restrict__ r0,
                            float* __restrict__ query, int* __restrict__ tnew) {
    __shared__ int s_isneg[BS];
    __shared__ int s_r0[BS];
    int t = threadIdx.x;
    if (t < BS) {
        int b = t;
        int hv = h_index[b * NEG1];
        int all = 1;
        for (int j = 1; j < NEG1; j++) all &= (h_index[b * NEG1 + j] == hv);
        s_isneg[b] = all;
        int h0v = all ? hv : t_index[b * NEG1];
        int r0v = all ? r_index[b * NEG1] : r_index[b * NEG1] + 64;
        s_r0[b] = r0v;
        h0[b] = h0v;
        r0[b] = r0v;
    }
    __syncthreads();
    {
        int b = t >> 5, dd = t & 31;
        query[t] = rel_query[s_r0[b] * DDIM + dd];
    }
    for (int idx = t; idx < BS * NEG1; idx += 256) {
        int b = idx / NEG1;
        tnew[idx] = s_isneg[b] ? t_index[idx] : h_index[idx];
    }
}

__global__ void rel_kernel(const float* __restrict__ rel_query, const float* __restrict__ Wrel,
                           const float* __restrict__ brel, float* __restrict__ rel_all) {
    int idx = blockIdx.x * 256 + threadIdx.x;
    if (idx >= NLAYER * NRELX2 * DDIM) return;
    int i  = idx >> 12;          // / 4096
    int q  = (idx >> 5) & 127;
    int dd = idx & 31;
    float acc = brel[i * DDIM + dd];
    #pragma unroll
    for (int k = 0; k < DDIM; k++)
        acc = fmaf(rel_query[q * DDIM + k], Wrel[i * DDIM * DDIM + k * DDIM + dd], acc);
    rel_all[idx] = acc;
}

// wg2[layer][step][dd][16]: the 13 weights consumed by lane dd at step,
// lane-contiguous and padded to 16 floats -> 4x global_load_dwordx4/step.
// wg2[...][j] = Wlin[layer][k_j(dd)][(dd+step)&31]
__global__ void wg_kernel(const float* __restrict__ Wlin, float* __restrict__ wg2) {
    int idx = blockIdx.x * 256 + threadIdx.x;       // NLAYER*32*32*16
    if (idx >= NLAYER * 32 * 32 * 16) return;
    int j  = idx & 15;
    int dd = (idx >> 4) & 31;
    int step  = (idx >> 9) & 31;
    int layer = idx >> 14;
    float v = 0.f;
    if (j < 13) {
        int k;
        if (j == 0) k = dd;
        else { int s = (j - 1) / 3, scl = (j - 1) % 3; k = 32 + (dd * 4 + s) * 3 + scl; }
        int col = (dd + step) & 31;
        v = Wlin[(layer * INW + k) * DDIM + col];
    }
    wg2[idx] = v;
}

__global__ void init_x_kernel(float* __restrict__ x, const int* __restrict__ h0,
                              const float* __restrict__ query) {
    int i = blockIdx.x * 256 + threadIdx.x;
    if (i >= NNODE * FEAT) return;
    int n = i >> 8;
    int t = i & 255;
    int b = t >> 5;
    x[i] = (h0[b] == n) ? query[t] : 0.f;
}

// ---------------------------------------------------------------- main layer
// Per block: 10 nodes, ONE group, 7 raw stats/node (13 FMA/node/step GSTEP).
// Weights lane-contiguous: 4x dwordx4 loads per step (was 13 dword loads).
// Systolic accumulator rotation, 1 ds_bpermute per acc per step.

#define STATS_COMP(U, NODE) {                                                 \
    int n_ = (NODE);                                                          \
    float bv_ = (h0b == n_) ? q : 0.f;                                        \
    float sum_ = bv_, ssq_ = bv_ * bv_, vmx_ = bv_, vmn_ = bv_;               \
    int e0_ = row_ptr[n_], e1_ = row_ptr[n_ + 1];                             \
    xm##U = x_in[n_ * FEAT + t];                                              \
    int e_ = e0_;                                                             \
    for (; e_ + 3 < e1_; e_ += 4) {                                           \
        int pa_ = csr_pack[e_];                                               \
        int pb_ = csr_pack[e_ + 1];                                           \
        int pc_ = csr_pack[e_ + 2];                                           \
        int pd_ = csr_pack[e_ + 3];                                           \
        float xa_ = x_in[(pa_ >> 16) * FEAT + t];                             \
        float xb_ = x_in[(pb_ >> 16) * FEAT + t];                             \
        float xc_ = x_in[(pc_ >> 16) * FEAT + t];                             \
        float xd_ = x_in[(pd_ >> 16) * FEAT + t];                             \
        float ra_ = s_rel[((pa_ & 0xFFFF) << 5) + dd];                        \
        float rb_ = s_rel[((pb_ & 0xFFFF) << 5) + dd];                        \
        float rc_ = s_rel[((pc_ & 0xFFFF) << 5) + dd];                        \
        float rd_ = s_rel[((pd_ & 0xFFFF) << 5) + dd];                        \
        float ma_ = xa_ * ra_, mb_ = xb_ * rb_;                               \
        float mc_ = xc_ * rc_, md_ = xd_ * rd_;                               \
        sum_ += ((ma_ + mb_) + (mc_ + md_));                                  \
        ssq_ = fmaf(ma_, ma_, ssq_); ssq_ = fmaf(mb_, mb_, ssq_);             \
        ssq_ = fmaf(mc_, mc_, ssq_); ssq_ = fmaf(md_, md_, ssq_);             \
        vmx_ = fmaxf(vmx_, fmaxf(fmaxf(ma_, mb_), fmaxf(mc_, md_)));         \
        vmn_ = fminf(vmn_, fminf(fminf(ma_, mb_), fminf(mc_, md_)));         \
    }                                                                         \
    for (; e_ < e1_; ++e_) {                                                  \
        int p_  = csr_pack[e_];                                               \
        float m_ = x_in[(p_ >> 16) * FEAT + t]                                \
                   * s_rel[((p_ & 0xFFFF) << 5) + dd];                        \
        sum_ += m_; ssq_ = fmaf(m_, m_, ssq_);                                \
        vmx_ = fmaxf(vmx_, m_); vmn_ = fminf(vmn_, m_);                       \
    }                                                                         \
    float dv_ = dinv[n_];                                                     \
    mean##U = sum_ * dv_;                                                     \
    float sq_ = ssq_ * dv_;                                                   \
    mx##U = vmx_; mn##U = vmn_;                                               \
    sd##U = sqrtf(fmaxf(sq_ - mean##U * mean##U, 1e-6f));                     \
    float sv_ = sc[n_];                                                       \
    sv##U = sv_; s2##U = 1.0f / fmaxf(sv_, 0.01f);                            \
}

#define SDECL(U) float xm##U, mean##U, mx##U, mn##U, sd##U, sv##U, s2##U;

#define GSTEP(U) {                                                            \
    float a_ = acc##U;                                                        \
    a_ = fmaf(xm##U, w0, a_);                                                 \
    float t0_ = fmaf(sv##U, w2,  w1);  t0_ = fmaf(s2##U, w3,  t0_);           \
    a_ = fmaf(mean##U, t0_, a_);                                              \
    float t1_ = fmaf(sv##U, w5,  w4);  t1_ = fmaf(s2##U, w6,  t1_);           \
    a_ = fmaf(mx##U,   t1_, a_);                                              \
    float t2_ = fmaf(sv##U, w8,  w7);  t2_ = fmaf(s2##U, w9,  t2_);           \
    a_ = fmaf(mn##U,   t2_, a_);                                              \
    float t3_ = fmaf(sv##U, w11, w10); t3_ = fmaf(s2##U, w12, t3_);           \
    a_ = fmaf(sd##U,   t3_, a_);                                              \
    acc##U = a_;                                                              \
}

#define ROT(U) acc##U = __int_as_float(__builtin_amdgcn_ds_bpermute(          \
                            bperm_addr, __float_as_int(acc##U)));

#define LNSTORE(U, NODE) {                                                    \
    int n_ = (NODE);                                                          \
    float v_ = acc##U;                                                        \
    float s1_ = v_;                                                           \
    s1_ += __shfl_xor(s1_, 16, 32); s1_ += __shfl_xor(s1_, 8, 32);            \
    s1_ += __shfl_xor(s1_, 4, 32);  s1_ += __shfl_xor(s1_, 2, 32);            \
    s1_ += __shfl_xor(s1_, 1, 32);                                            \
    float lm_ = s1_ * (1.0f / 32.0f);                                         \
    float dl_ = v_ - lm_;                                                     \
    float p2_ = dl_ * dl_;                                                    \
    p2_ += __shfl_xor(p2_, 16, 32); p2_ += __shfl_xor(p2_, 8, 32);            \
    p2_ += __shfl_xor(p2_, 4, 32);  p2_ += __shfl_xor(p2_, 2, 32);            \
    p2_ += __shfl_xor(p2_, 1, 32);                                            \
    float var_ = p2_ * (1.0f / 32.0f);                                        \
    float y_ = dl_ / sqrtf(var_ + 1e-5f) * gdd + bdd;                         \
    y_ = fmaxf(y_, 0.0f);                                                     \
    x_out[n_ * FEAT + t] = y_ + xm##U;                                        \
}

__global__ __launch_bounds__(256, 2) void layer_kernel(
    const float* __restrict__ x_in, float* __restrict__ x_out,
    const int* __restrict__ row_ptr, const int* __restrict__ csr_pack,
    const float* __restrict__ rel_i,     // [128][32]
    const float* __restrict__ wg_i,      // [32][32][16] lane-contiguous
    const float* __restrict__ blin_i, const float* __restrict__ g_i,
    const float* __restrict__ b_i,
    const float* __restrict__ dinv, const float* __restrict__ sc,
    const int* __restrict__ h0, const float* __restrict__ query) {
    int t  = threadIdx.x;
    int b  = t >> 5, dd = t & 31;
    int lane = t & 63;
    __shared__ float s_rel[NRELX2 * DDIM];   // 16 KB

    for (int k = t; k < NRELX2 * DDIM; k += 256) s_rel[k] = rel_i[k];

    float q   = query[t];
    int   h0b = h0[b];
    float gdd = g_i[dd], bdd = b_i[dd], bl = blin_i[dd];
    // rotate-down-by-1 within each 32-lane half of the wave (pull from lane+1)
    int bperm_addr = ((((lane + 1) & 31) | (lane & 32)) << 2);
    __syncthreads();

    int nbase = blockIdx.x * NPB;
    SDECL(0) SDECL(1) SDECL(2) SDECL(3) SDECL(4)
    SDECL(5) SDECL(6) SDECL(7) SDECL(8) SDECL(9)
    STATS_COMP(0, nbase + 0)
    STATS_COMP(1, nbase + 1)
    STATS_COMP(2, nbase + 2)
    STATS_COMP(3, nbase + 3)
    STATS_COMP(4, nbase + 4)
    STATS_COMP(5, nbase + 5)
    STATS_COMP(6, nbase + 6)
    STATS_COMP(7, nbase + 7)
    STATS_COMP(8, nbase + 8)
    STATS_COMP(9, nbase + 9)

    float acc0 = bl, acc1 = bl, acc2 = bl, acc3 = bl, acc4 = bl;
    float acc5 = bl, acc6 = bl, acc7 = bl, acc8 = bl, acc9 = bl;

    const float4* wbase = (const float4*)(wg_i + (dd << 4));
    #pragma unroll 1
    for (int i = 0; i < 32; ++i) {
        const float4* wp = wbase + (i << 7);   // i*32*16 floats = i*128 float4
        float4 wa = wp[0], wb = wp[1], wc = wp[2], wd = wp[3];
        float w0  = wa.x, w1  = wa.y, w2  = wa.z, w3  = wa.w;
        float w4  = wb.x, w5  = wb.y, w6  = wb.z, w7  = wb.w;
        float w8  = wc.x, w9  = wc.y, w10 = wc.z, w11 = wc.w;
        float w12 = wd.x;
        GSTEP(0) GSTEP(1) GSTEP(2) GSTEP(3) GSTEP(4)
        GSTEP(5) GSTEP(6) GSTEP(7) GSTEP(8) GSTEP(9)
        ROT(0) ROT(1) ROT(2) ROT(3) ROT(4)
        ROT(5) ROT(6) ROT(7) ROT(8) ROT(9)
    }
    // 32 rotations = identity: lane dd again holds col dd

    LNSTORE(0, nbase + 0)
    LNSTORE(1, nbase + 1)
    LNSTORE(2, nbase + 2)
    LNSTORE(3, nbase + 3)
    LNSTORE(4, nbase + 4)
    LNSTORE(5, nbase + 5)
    LNSTORE(6, nbase + 6)
    LNSTORE(7, nbase + 7)
    LNSTORE(8, nbase + 8)
    LNSTORE(9, nbase + 9)
}

// ---------------------------------------------------------------- readout
__global__ void score_kernel(const float* __restrict__ x, const int* __restrict__ tnew,
                             const float* __restrict__ query,
                             const float* __restrict__ W1, const float* __restrict__ b1,
                             const float* __restrict__ W2, const float* __restrict__ b2,
                             float* __restrict__ out) {
    int idx = blockIdx.x;         // b*33+j
    int b = idx / NEG1;
    int k = threadIdx.x;          // 0..63
    __shared__ float v[64];
    int tnode = tnew[idx];
    if (k < 32) v[k] = x[tnode * FEAT + b * DDIM + k];
    else        v[k] = query[b * DDIM + (k - 32)];
    __syncthreads();
    float acc = b1[k];
    #pragma unroll
    for (int l = 0; l < 64; l++) acc = fmaf(v[l], W1[l * 64 + k], acc);
    acc = fmaxf(acc, 0.f);
    float p = acc * W2[k];
    #pragma unroll
    for (int m = 32; m >= 1; m >>= 1) p += __shfl_xor(p, m);
    if (k == 0) out[idx] = p + b2[0];
}

// ---------------------------------------------------------------- launch
extern "C" void kernel_launch(void* const* d_in, const int* in_sizes, int n_in,
                              void* d_out, int out_size, void* d_ws, size_t ws_size,
                              hipStream_t stream) {
    const int* edge_src  = (const int*)d_in[0];
    const int* edge_dst  = (const int*)d_in[1];
    const int* edge_type = (const int*)d_in[2];
    const int* h_index   = (const int*)d_in[3];
    const int* t_index   = (const int*)d_in[4];
    const int* r_index   = (const int*)d_in[5];
    const float* rel_query = (const float*)d_in[7];
    const float* Wrel    = (const float*)d_in[8];
    const float* brel    = (const float*)d_in[9];
    const float* Wlin    = (const float*)d_in[10];
    const float* blin    = (const float*)d_in[11];
    const float* ln_g    = (const float*)d_in[12];
    const float* ln_b    = (const float*)d_in[13];
    const float* W1      = (const float*)d_in[14];
    const float* b1      = (const float*)d_in[15];
    const float* W2      = (const float*)d_in[16];
    const float* b2      = (const float*)d_in[17];

    const int N  = NNODE;
    const int E  = in_sizes[0];
    const int E2 = 2 * E;

    char* p = (char*)d_ws;
    auto carve = [&](size_t bytes) {
        void* r = (void*)p;
        p += (bytes + 255) & ~(size_t)255;
        return r;
    };
    float* x0      = (float*)carve((size_t)N * FEAT * 4);
    float* x1      = (float*)carve((size_t)N * FEAT * 4);
    int*   cnt     = (int*)carve((size_t)N * 4);
    int*   row_ptr = (int*)carve((size_t)(N + 1) * 4);
    int*   cursor  = (int*)carve((size_t)N * 4);
    int*   csr_pack= (int*)carve((size_t)E2 * 4);
    float* dinv    = (float*)carve((size_t)N * 4);
    float* logdeg  = (float*)carve((size_t)N * 4);
    float* scn     = (float*)carve((size_t)N * 4);
    float* meanp   = (float*)carve(16);
    float* rel_all = (float*)carve((size_t)NLAYER * NRELX2 * DDIM * 4);
    float* wg2     = (float*)carve((size_t)NLAYER * 32 * 32 * 16 * 4);
    int*   h0      = (int*)carve(BS * 4);
    int*   r0      = (int*)carve(BS * 4);
    float* query   = (float*)carve(BS * DDIM * 4);
    int*   tnew    = (int*)carve(BS * NEG1 * 4);

    hipMemsetAsync(cnt, 0, (size_t)N * 4, stream);
    hipMemsetAsync(cursor, 0, (size_t)N * 4, stream);

    int eb = (E2 + 255) / 256;
    count_kernel<<<eb, 256, 0, stream>>>(edge_src, edge_dst, cnt, E);
    scan_kernel<<<1, 1024, 0, stream>>>(cnt, row_ptr, N);
    fill_kernel<<<eb, 256, 0, stream>>>(edge_src, edge_dst, edge_type, row_ptr,
                                        cursor, csr_pack, E);
    deg_kernel<<<(N + 255) / 256, 256, 0, stream>>>(cnt, dinv, logdeg, N);
    mean_kernel<<<1, 256, 0, stream>>>(logdeg, meanp, N);
    sc_kernel<<<(N + 255) / 256, 256, 0, stream>>>(logdeg, meanp, scn, N);
    prep_kernel<<<1, 256, 0, stream>>>(h_index, t_index, r_index, rel_query,
                                       h0, r0, query, tnew);
    rel_kernel<<<(NLAYER * NRELX2 * DDIM + 255) / 256, 256, 0, stream>>>(
        rel_query, Wrel, brel, rel_all);
    wg_kernel<<<(NLAYER * 32 * 32 * 16 + 255) / 256, 256, 0, stream>>>(Wlin, wg2);
    init_x_kernel<<<(N * FEAT + 255) / 256, 256, 0, stream>>>(x0, h0, query);

    float* xin = x0;
    float* xout = x1;
    for (int i = 0; i < NLAYER; ++i) {
        layer_kernel<<<N / NPB, 256, 0, stream>>>(
            xin, xout, row_ptr, csr_pack,
            rel_all + (size_t)i * NRELX2 * DDIM,
            wg2 + (size_t)i * 32 * 32 * 16,
            blin + (size_t)i * DDIM,
            ln_g + (size_t)i * DDIM,
            ln_b + (size_t)i * DDIM,
            dinv, scn, h0, query);
        float* tmp = xin; xin = xout; xout = tmp;
    }

    score_kernel<<<BS * NEG1, 64, 0, stream>>>(xin, tnew, query, W1, b1, W2, b2,
                                               (float*)d_out);
}

// Round 12
// 668.350 us; speedup vs baseline: 1.2268x; 1.2207x over previous
//
#include <hip/hip_runtime.h>
#include <hip/hip_bf16.h>

// Problem constants fixed by setup_inputs()
#define NNODE   20000
#define BS      8
#define NEG1    33
#define DDIM    32
#define NLAYER  6
#define NRELX2  128     // 2*N_REL
#define FEAT    256     // BS*DDIM
#define INW     416     // 13*DDIM
#define NPB     10      // nodes per block, ONE group -> grid 2000

// ---------------------------------------------------------------- precompute
__global__ void count_kernel(const int* __restrict__ es, const int* __restrict__ ed,
                             int* __restrict__ cnt, int E) {
    int i = blockIdx.x * 256 + threadIdx.x;
    if (i >= 2 * E) return;
    int dst = (i < E) ? ed[i] : es[i - E];
    atomicAdd(&cnt[dst], 1);
}

__global__ void scan_kernel(const int* __restrict__ cnt, int* __restrict__ row_ptr, int N) {
    __shared__ int sh[1024];
    __shared__ int s_carry;
    if (threadIdx.x == 0) { s_carry = 0; row_ptr[0] = 0; }
    __syncthreads();
    for (int base = 0; base < N; base += 1024) {
        int i = base + threadIdx.x;
        int v = (i < N) ? cnt[i] : 0;
        sh[threadIdx.x] = v;
        __syncthreads();
        for (int off = 1; off < 1024; off <<= 1) {
            int t = (threadIdx.x >= off) ? sh[threadIdx.x - off] : 0;
            __syncthreads();
            sh[threadIdx.x] += t;
            __syncthreads();
        }
        int carry = s_carry;
        if (i < N) row_ptr[i + 1] = carry + sh[threadIdx.x];
        __syncthreads();
        if (threadIdx.x == 1023) s_carry = carry + sh[1023];
        __syncthreads();
    }
}

// csr_pack = (src << 16) | etype   (src < 20000 < 65536, etype < 128)
__global__ void fill_kernel(const int* __restrict__ es, const int* __restrict__ ed,
                            const int* __restrict__ et, const int* __restrict__ row_ptr,
                            int* __restrict__ cursor, int* __restrict__ csr_pack, int E) {
    int i = blockIdx.x * 256 + threadIdx.x;
    if (i >= 2 * E) return;
    int src, dst, ty;
    if (i < E) { src = es[i]; dst = ed[i]; ty = et[i]; }
    else       { src = ed[i - E]; dst = es[i - E]; ty = et[i - E] + 64; }
    int pos = row_ptr[dst] + atomicAdd(&cursor[dst], 1);
    csr_pack[pos] = (src << 16) | ty;
}

__global__ void deg_kernel(const int* __restrict__ cnt, float* __restrict__ dinv,
                           float* __restrict__ logdeg, int N) {
    int n = blockIdx.x * 256 + threadIdx.x;
    if (n >= N) return;
    float deg = (float)cnt[n] + 1.0f;
    dinv[n] = 1.0f / deg;
    logdeg[n] = logf(deg);
}

__global__ void mean_kernel(const float* __restrict__ logdeg, float* __restrict__ meanout, int N) {
    __shared__ float sh[256];
    float s = 0.f;
    for (int i = threadIdx.x; i < N; i += 256) s += logdeg[i];
    sh[threadIdx.x] = s;
    __syncthreads();
    for (int off = 128; off > 0; off >>= 1) {
        if (threadIdx.x < off) sh[threadIdx.x] += sh[threadIdx.x + off];
        __syncthreads();
    }
    if (threadIdx.x == 0) meanout[0] = sh[0] / (float)N;
}

__global__ void sc_kernel(const float* __restrict__ logdeg, const float* __restrict__ meanp,
                          float* __restrict__ sc, int N) {
    int n = blockIdx.x * 256 + threadIdx.x;
    if (n >= N) return;
    sc[n] = logdeg[n] / meanp[0];
}

__global__ void prep_kernel(const int* __restrict__ h_index, const int* __restrict__ t_index,
                            const int* __restrict__ r_index, const float* __restrict__ rel_query,
                            int* __restrict__ h0, int* __restrict__ r0,
                            float* __restrict__ query, int* __restrict__ tnew) {
    __shared__ int s_isneg[BS];
    __shared__ int s_r0[BS];
    int t = threadIdx.x;
    if (t < BS) {
        int b = t;
        int hv = h_index[b * NEG1];
        int all = 1;
        for (int j = 1; j < NEG1; j++) all &= (h_index[b * NEG1 + j] == hv);
        s_isneg[b] = all;
        int h0v = all ? hv : t_index[b * NEG1];
        int r0v = all ? r_index[b * NEG1] : r_index[b * NEG1] + 64;
        s_r0[b] = r0v;
        h0[b] = h0v;
        r0[b] = r0v;
    }
    __syncthreads();
    {
        int b = t >> 5, dd = t & 31;
        query[t] = rel_query[s_r0[b] * DDIM + dd];
    }
    for (int idx = t; idx < BS * NEG1; idx += 256) {
        int b = idx / NEG1;
        tnew[idx] = s_isneg[b] ? t_index[idx] : h_index[idx];
    }
}

__global__ void rel_kernel(const float* __restrict__ rel_query, const float* __restrict__ Wrel,
                           const float* __restrict__ brel, float* __restrict__ rel_all) {
    int idx = blockIdx.x * 256 + threadIdx.x;
    if (idx >= NLAYER * NRELX2 * DDIM) return;
    int i  = idx >> 12;          // / 4096
    int q  = (idx >> 5) & 127;
    int dd = idx & 31;
    float acc = brel[i * DDIM + dd];
    #pragma unroll
    for (int k = 0; k < DDIM; k++)
        acc = fmaf(rel_query[q * DDIM + k], Wrel[i * DDIM * DDIM + k * DDIM + dd], acc);
    rel_all[idx] = acc;
}

// Wg[layer][step][j][dd] = Wlin[layer][k_j(dd)][(dd+step)&31]
__global__ void wg_kernel(const float* __restrict__ Wlin, float* __restrict__ wg) {
    int idx = blockIdx.x * 256 + threadIdx.x;       // NLAYER*32*13*32
    if (idx >= NLAYER * 32 * 13 * 32) return;
    int dd = idx & 31;
    int r  = idx >> 5;
    int j  = r % 13;
    int r2 = r / 13;
    int step  = r2 & 31;
    int layer = r2 >> 5;
    int k;
    if (j == 0) k = dd;
    else { int s = (j - 1) / 3, scl = (j - 1) % 3; k = 32 + (dd * 4 + s) * 3 + scl; }
    int col = (dd + step) & 31;
    wg[idx] = Wlin[(layer * INW + k) * DDIM + col];
}

__global__ void init_x_kernel(float* __restrict__ x, const int* __restrict__ h0,
                              const float* __restrict__ query) {
    int i = blockIdx.x * 256 + threadIdx.x;
    if (i >= NNODE * FEAT) return;
    int n = i >> 8;
    int t = i & 255;
    int b = t >> 5;
    x[i] = (h0[b] == n) ? query[t] : 0.f;
}

// ---------------------------------------------------------------- main layer
// Per block: 10 nodes, ONE group, 7 raw stats/node. GEMM: systolic rotation,
// weights REGISTER-DOUBLE-BUFFERED (next step's 13 loads issue before this
// step's 130 FMAs + 10 rotates -> L2 latency hidden behind independent work).

#define STATS_COMP(U, NODE) {                                                 \
    int n_ = (NODE);                                                          \
    float bv_ = (h0b == n_) ? q : 0.f;                                        \
    float sum_ = bv_, ssq_ = bv_ * bv_, vmx_ = bv_, vmn_ = bv_;               \
    int e0_ = row_ptr[n_], e1_ = row_ptr[n_ + 1];                             \
    xm##U = x_in[n_ * FEAT + t];                                              \
    int e_ = e0_;                                                             \
    for (; e_ + 3 < e1_; e_ += 4) {                                           \
        int pa_ = csr_pack[e_];                                               \
        int pb_ = csr_pack[e_ + 1];                                           \
        int pc_ = csr_pack[e_ + 2];                                           \
        int pd_ = csr_pack[e_ + 3];                                           \
        float xa_ = x_in[(pa_ >> 16) * FEAT + t];                             \
        float xb_ = x_in[(pb_ >> 16) * FEAT + t];                             \
        float xc_ = x_in[(pc_ >> 16) * FEAT + t];                             \
        float xd_ = x_in[(pd_ >> 16) * FEAT + t];                             \
        float ra_ = s_rel[((pa_ & 0xFFFF) << 5) + dd];                        \
        float rb_ = s_rel[((pb_ & 0xFFFF) << 5) + dd];                        \
        float rc_ = s_rel[((pc_ & 0xFFFF) << 5) + dd];                        \
        float rd_ = s_rel[((pd_ & 0xFFFF) << 5) + dd];                        \
        float ma_ = xa_ * ra_, mb_ = xb_ * rb_;                               \
        float mc_ = xc_ * rc_, md_ = xd_ * rd_;                               \
        sum_ += ((ma_ + mb_) + (mc_ + md_));                                  \
        ssq_ = fmaf(ma_, ma_, ssq_); ssq_ = fmaf(mb_, mb_, ssq_);             \
        ssq_ = fmaf(mc_, mc_, ssq_); ssq_ = fmaf(md_, md_, ssq_);             \
        vmx_ = fmaxf(vmx_, fmaxf(fmaxf(ma_, mb_), fmaxf(mc_, md_)));         \
        vmn_ = fminf(vmn_, fminf(fminf(ma_, mb_), fminf(mc_, md_)));         \
    }                                                                         \
    for (; e_ < e1_; ++e_) {                                                  \
        int p_  = csr_pack[e_];                                               \
        float m_ = x_in[(p_ >> 16) * FEAT + t]                                \
                   * s_rel[((p_ & 0xFFFF) << 5) + dd];                        \
        sum_ += m_; ssq_ = fmaf(m_, m_, ssq_);                                \
        vmx_ = fmaxf(vmx_, m_); vmn_ = fminf(vmn_, m_);                       \
    }                                                                         \
    float dv_ = dinv[n_];                                                     \
    mean##U = sum_ * dv_;                                                     \
    float sq_ = ssq_ * dv_;                                                   \
    mx##U = vmx_; mn##U = vmn_;                                               \
    sd##U = sqrtf(fmaxf(sq_ - mean##U * mean##U, 1e-6f));                     \
    float sv_ = sc[n_];                                                       \
    sv##U = sv_; s2##U = 1.0f / fmaxf(sv_, 0.01f);                            \
}

#define SDECL(U) float xm##U, mean##U, mx##U, mn##U, sd##U, sv##U, s2##U;

#define GSTEP(U) {                                                            \
    float a_ = acc##U;                                                        \
    a_ = fmaf(xm##U, cw0, a_);                                                \
    float t0_ = fmaf(sv##U, cw2,  cw1);  t0_ = fmaf(s2##U, cw3,  t0_);        \
    a_ = fmaf(mean##U, t0_, a_);                                              \
    float t1_ = fmaf(sv##U, cw5,  cw4);  t1_ = fmaf(s2##U, cw6,  t1_);        \
    a_ = fmaf(mx##U,   t1_, a_);                                              \
    float t2_ = fmaf(sv##U, cw8,  cw7);  t2_ = fmaf(s2##U, cw9,  t2_);        \
    a_ = fmaf(mn##U,   t2_, a_);                                              \
    float t3_ = fmaf(sv##U, cw11, cw10); t3_ = fmaf(s2##U, cw12, t3_);        \
    a_ = fmaf(sd##U,   t3_, a_);                                              \
    acc##U = a_;                                                              \
}

#define ROT(U) acc##U = __int_as_float(__builtin_amdgcn_ds_bpermute(          \
                            bperm_addr, __float_as_int(acc##U)));

#define LNSTORE(U, NODE) {                                                    \
    int n_ = (NODE);                                                          \
    float v_ = acc##U;                                                        \
    float s1_ = v_;                                                           \
    s1_ += __shfl_xor(s1_, 16, 32); s1_ += __shfl_xor(s1_, 8, 32);            \
    s1_ += __shfl_xor(s1_, 4, 32);  s1_ += __shfl_xor(s1_, 2, 32);            \
    s1_ += __shfl_xor(s1_, 1, 32);                                            \
    float lm_ = s1_ * (1.0f / 32.0f);                                         \
    float dl_ = v_ - lm_;                                                     \
    float p2_ = dl_ * dl_;                                                    \
    p2_ += __shfl_xor(p2_, 16, 32); p2_ += __shfl_xor(p2_, 8, 32);            \
    p2_ += __shfl_xor(p2_, 4, 32);  p2_ += __shfl_xor(p2_, 2, 32);            \
    p2_ += __shfl_xor(p2_, 1, 32);                                            \
    float var_ = p2_ * (1.0f / 32.0f);                                        \
    float y_ = dl_ / sqrtf(var_ + 1e-5f) * gdd + bdd;                         \
    y_ = fmaxf(y_, 0.0f);                                                     \
    x_out[n_ * FEAT + t] = y_ + xm##U;                                        \
}

__global__ __launch_bounds__(256, 2) void layer_kernel(
    const float* __restrict__ x_in, float* __restrict__ x_out,
    const int* __restrict__ row_ptr, const int* __restrict__ csr_pack,
    const float* __restrict__ rel_i,     // [128][32]
    const float* __restrict__ wg_i,      // [32][13][32]
    const float* __restrict__ blin_i, const float* __restrict__ g_i,
    const float* __restrict__ b_i,
    const float* __restrict__ dinv, const float* __restrict__ sc,
    const int* __restrict__ h0, const float* __restrict__ query) {
    int t  = threadIdx.x;
    int b  = t >> 5, dd = t & 31;
    int lane = t & 63;
    __shared__ float s_rel[NRELX2 * DDIM];   // 16 KB

    for (int k = t; k < NRELX2 * DDIM; k += 256) s_rel[k] = rel_i[k];

    float q   = query[t];
    int   h0b = h0[b];
    float gdd = g_i[dd], bdd = b_i[dd], bl = blin_i[dd];
    // rotate-down-by-1 within each 32-lane half of the wave (pull from lane+1)
    int bperm_addr = ((((lane + 1) & 31) | (lane & 32)) << 2);
    __syncthreads();

    int nbase = blockIdx.x * NPB;
    SDECL(0) SDECL(1) SDECL(2) SDECL(3) SDECL(4)
    SDECL(5) SDECL(6) SDECL(7) SDECL(8) SDECL(9)
    STATS_COMP(0, nbase + 0)
    STATS_COMP(1, nbase + 1)
    STATS_COMP(2, nbase + 2)
    STATS_COMP(3, nbase + 3)
    STATS_COMP(4, nbase + 4)
    STATS_COMP(5, nbase + 5)
    STATS_COMP(6, nbase + 6)
    STATS_COMP(7, nbase + 7)
    STATS_COMP(8, nbase + 8)
    STATS_COMP(9, nbase + 9)

    float acc0 = bl, acc1 = bl, acc2 = bl, acc3 = bl, acc4 = bl;
    float acc5 = bl, acc6 = bl, acc7 = bl, acc8 = bl, acc9 = bl;

    // prologue: load step 0 weights
    const float* wp0 = wg_i + dd;
    float cw0  = wp0[0 * 32],  cw1  = wp0[1 * 32],  cw2  = wp0[2 * 32];
    float cw3  = wp0[3 * 32],  cw4  = wp0[4 * 32],  cw5  = wp0[5 * 32];
    float cw6  = wp0[6 * 32],  cw7  = wp0[7 * 32],  cw8  = wp0[8 * 32];
    float cw9  = wp0[9 * 32],  cw10 = wp0[10 * 32], cw11 = wp0[11 * 32];
    float cw12 = wp0[12 * 32];

    #pragma unroll 1
    for (int i = 0; i < 32; ++i) {
        // prefetch next step's weights (wraps on last iter; values unused)
        const float* wn = wg_i + ((i + 1) & 31) * 416 + dd;
        float nw0  = wn[0 * 32],  nw1  = wn[1 * 32],  nw2  = wn[2 * 32];
        float nw3  = wn[3 * 32],  nw4  = wn[4 * 32],  nw5  = wn[5 * 32];
        float nw6  = wn[6 * 32],  nw7  = wn[7 * 32],  nw8  = wn[8 * 32];
        float nw9  = wn[9 * 32],  nw10 = wn[10 * 32], nw11 = wn[11 * 32];
        float nw12 = wn[12 * 32];

        GSTEP(0) GSTEP(1) GSTEP(2) GSTEP(3) GSTEP(4)
        GSTEP(5) GSTEP(6) GSTEP(7) GSTEP(8) GSTEP(9)
        ROT(0) ROT(1) ROT(2) ROT(3) ROT(4)
        ROT(5) ROT(6) ROT(7) ROT(8) ROT(9)

        cw0 = nw0;  cw1 = nw1;  cw2 = nw2;  cw3 = nw3;  cw4 = nw4;
        cw5 = nw5;  cw6 = nw6;  cw7 = nw7;  cw8 = nw8;  cw9 = nw9;
        cw10 = nw10; cw11 = nw11; cw12 = nw12;
    }
    // 32 rotations = identity: lane dd again holds col dd

    LNSTORE(0, nbase + 0)
    LNSTORE(1, nbase + 1)
    LNSTORE(2, nbase + 2)
    LNSTORE(3, nbase + 3)
    LNSTORE(4, nbase + 4)
    LNSTORE(5, nbase + 5)
    LNSTORE(6, nbase + 6)
    LNSTORE(7, nbase + 7)
    LNSTORE(8, nbase + 8)
    LNSTORE(9, nbase + 9)
}

// ---------------------------------------------------------------- readout
__global__ void score_kernel(const float* __restrict__ x, const int* __restrict__ tnew,
                             const float* __restrict__ query,
                             const float* __restrict__ W1, const float* __restrict__ b1,
                             const float* __restrict__ W2, const float* __restrict__ b2,
                             float* __restrict__ out) {
    int idx = blockIdx.x;         // b*33+j
    int b = idx / NEG1;
    int k = threadIdx.x;          // 0..63
    __shared__ float v[64];
    int tnode = tnew[idx];
    if (k < 32) v[k] = x[tnode * FEAT + b * DDIM + k];
    else        v[k] = query[b * DDIM + (k - 32)];
    __syncthreads();
    float acc = b1[k];
    #pragma unroll
    for (int l = 0; l < 64; l++) acc = fmaf(v[l], W1[l * 64 + k], acc);
    acc = fmaxf(acc, 0.f);
    float p = acc * W2[k];
    #pragma unroll
    for (int m = 32; m >= 1; m >>= 1) p += __shfl_xor(p, m);
    if (k == 0) out[idx] = p + b2[0];
}

// ---------------------------------------------------------------- launch
extern "C" void kernel_launch(void* const* d_in, const int* in_sizes, int n_in,
                              void* d_out, int out_size, void* d_ws, size_t ws_size,
                              hipStream_t stream) {
    const int* edge_src  = (const int*)d_in[0];
    const int* edge_dst  = (const int*)d_in[1];
    const int* edge_type = (const int*)d_in[2];
    const int* h_index   = (const int*)d_in[3];
    const int* t_index   = (const int*)d_in[4];
    const int* r_index   = (const int*)d_in[5];
    const float* rel_query = (const float*)d_in[7];
    const float* Wrel    = (const float*)d_in[8];
    const float* brel    = (const float*)d_in[9];
    const float* Wlin    = (const float*)d_in[10];
    const float* blin    = (const float*)d_in[11];
    const float* ln_g    = (const float*)d_in[12];
    const float* ln_b    = (const float*)d_in[13];
    const float* W1      = (const float*)d_in[14];
    const float* b1      = (const float*)d_in[15];
    const float* W2      = (const float*)d_in[16];
    const float* b2      = (const float*)d_in[17];

    const int N  = NNODE;
    const int E  = in_sizes[0];
    const int E2 = 2 * E;

    char* p = (char*)d_ws;
    auto carve = [&](size_t bytes) {
        void* r = (void*)p;
        p += (bytes + 255) & ~(size_t)255;
        return r;
    };
    float* x0      = (float*)carve((size_t)N * FEAT * 4);
    float* x1      = (float*)carve((size_t)N * FEAT * 4);
    int*   cnt     = (int*)carve((size_t)N * 4);
    int*   row_ptr = (int*)carve((size_t)(N + 1) * 4);
    int*   cursor  = (int*)carve((size_t)N * 4);
    int*   csr_pack= (int*)carve((size_t)E2 * 4);
    float* dinv    = (float*)carve((size_t)N * 4);
    float* logdeg  = (float*)carve((size_t)N * 4);
    float* scn     = (float*)carve((size_t)N * 4);
    float* meanp   = (float*)carve(16);
    float* rel_all = (float*)carve((size_t)NLAYER * NRELX2 * DDIM * 4);
    float* wg      = (float*)carve((size_t)NLAYER * 32 * 13 * 32 * 4);
    int*   h0      = (int*)carve(BS * 4);
    int*   r0      = (int*)carve(BS * 4);
    float* query   = (float*)carve(BS * DDIM * 4);
    int*   tnew    = (int*)carve(BS * NEG1 * 4);

    hipMemsetAsync(cnt, 0, (size_t)N * 4, stream);
    hipMemsetAsync(cursor, 0, (size_t)N * 4, stream);

    int eb = (E2 + 255) / 256;
    count_kernel<<<eb, 256, 0, stream>>>(edge_src, edge_dst, cnt, E);
    scan_kernel<<<1, 1024, 0, stream>>>(cnt, row_ptr, N);
    fill_kernel<<<eb, 256, 0, stream>>>(edge_src, edge_dst, edge_type, row_ptr,
                                        cursor, csr_pack, E);
    deg_kernel<<<(N + 255) / 256, 256, 0, stream>>>(cnt, dinv, logdeg, N);
    mean_kernel<<<1, 256, 0, stream>>>(logdeg, meanp, N);
    sc_kernel<<<(N + 255) / 256, 256, 0, stream>>>(logdeg, meanp, scn, N);
    prep_kernel<<<1, 256, 0, stream>>>(h_index, t_index, r_index, rel_query,
                                       h0, r0, query, tnew);
    rel_kernel<<<(NLAYER * NRELX2 * DDIM + 255) / 256, 256, 0, stream>>>(
        rel_query, Wrel, brel, rel_all);
    wg_kernel<<<(NLAYER * 32 * 13 * 32 + 255) / 256, 256, 0, stream>>>(Wlin, wg);
    init_x_kernel<<<(N * FEAT + 255) / 256, 256, 0, stream>>>(x0, h0, query);

    float* xin = x0;
    float* xout = x1;
    for (int i = 0; i < NLAYER; ++i) {
        layer_kernel<<<N / NPB, 256, 0, stream>>>(
            xin, xout, row_ptr, csr_pack,
            rel_all + (size_t)i * NRELX2 * DDIM,
            wg + (size_t)i * 32 * 13 * 32,
            blin + (size_t)i * DDIM,
            ln_g + (size_t)i * DDIM,
            ln_b + (size_t)i * DDIM,
            dinv, scn, h0, query);
        float* tmp = xin; xin = xout; xout = tmp;
    }

    score_kernel<<<BS * NEG1, 64, 0, stream>>>(xin, tnew, query, W1, b1, W2, b2,
                                               (float*)d_out);
}

// Round 13
// 667.241 us; speedup vs baseline: 1.2289x; 1.0017x over previous
//
#include <hip/hip_runtime.h>
#include <hip/hip_bf16.h>

// Problem constants fixed by setup_inputs()
#define NNODE   20000
#define BS      8
#define NEG1    33
#define DDIM    32
#define NLAYER  6
#define NRELX2  128     // 2*N_REL
#define FEAT    256     // BS*DDIM
#define INW     416     // 13*DDIM
#define NPB     10      // nodes per block, ONE group -> grid 2000

// ---------------------------------------------------------------- precompute
__global__ void count_kernel(const int* __restrict__ es, const int* __restrict__ ed,
                             int* __restrict__ cnt, int E) {
    int i = blockIdx.x * 256 + threadIdx.x;
    if (i >= 2 * E) return;
    int dst = (i < E) ? ed[i] : es[i - E];
    atomicAdd(&cnt[dst], 1);
}

__global__ void scan_kernel(const int* __restrict__ cnt, int* __restrict__ row_ptr, int N) {
    __shared__ int sh[1024];
    __shared__ int s_carry;
    if (threadIdx.x == 0) { s_carry = 0; row_ptr[0] = 0; }
    __syncthreads();
    for (int base = 0; base < N; base += 1024) {
        int i = base + threadIdx.x;
        int v = (i < N) ? cnt[i] : 0;
        sh[threadIdx.x] = v;
        __syncthreads();
        for (int off = 1; off < 1024; off <<= 1) {
            int t = (threadIdx.x >= off) ? sh[threadIdx.x - off] : 0;
            __syncthreads();
            sh[threadIdx.x] += t;
            __syncthreads();
        }
        int carry = s_carry;
        if (i < N) row_ptr[i + 1] = carry + sh[threadIdx.x];
        __syncthreads();
        if (threadIdx.x == 1023) s_carry = carry + sh[1023];
        __syncthreads();
    }
}

// csr_pack = (src << 16) | etype   (src < 20000 < 65536, etype < 128)
__global__ void fill_kernel(const int* __restrict__ es, const int* __restrict__ ed,
                            const int* __restrict__ et, const int* __restrict__ row_ptr,
                            int* __restrict__ cursor, int* __restrict__ csr_pack, int E) {
    int i = blockIdx.x * 256 + threadIdx.x;
    if (i >= 2 * E) return;
    int src, dst, ty;
    if (i < E) { src = es[i]; dst = ed[i]; ty = et[i]; }
    else       { src = ed[i - E]; dst = es[i - E]; ty = et[i - E] + 64; }
    int pos = row_ptr[dst] + atomicAdd(&cursor[dst], 1);
    csr_pack[pos] = (src << 16) | ty;
}

__global__ void deg_kernel(const int* __restrict__ cnt, float* __restrict__ dinv,
                           float* __restrict__ logdeg, int N) {
    int n = blockIdx.x * 256 + threadIdx.x;
    if (n >= N) return;
    float deg = (float)cnt[n] + 1.0f;
    dinv[n] = 1.0f / deg;
    logdeg[n] = logf(deg);
}

__global__ void mean_kernel(const float* __restrict__ logdeg, float* __restrict__ meanout, int N) {
    __shared__ float sh[256];
    float s = 0.f;
    for (int i = threadIdx.x; i < N; i += 256) s += logdeg[i];
    sh[threadIdx.x] = s;
    __syncthreads();
    for (int off = 128; off > 0; off >>= 1) {
        if (threadIdx.x < off) sh[threadIdx.x] += sh[threadIdx.x + off];
        __syncthreads();
    }
    if (threadIdx.x == 0) meanout[0] = sh[0] / (float)N;
}

__global__ void sc_kernel(const float* __restrict__ logdeg, const float* __restrict__ meanp,
                          float* __restrict__ sc, int N) {
    int n = blockIdx.x * 256 + threadIdx.x;
    if (n >= N) return;
    sc[n] = logdeg[n] / meanp[0];
}

__global__ void prep_kernel(const int* __restrict__ h_index, const int* __restrict__ t_index,
                            const int* __restrict__ r_index, const float* __restrict__ rel_query,
                            int* __restrict__ h0, int* __restrict__ r0,
                            float* __restrict__ query, int* __restrict__ tnew) {
    __shared__ int s_isneg[BS];
    __shared__ int s_r0[BS];
    int t = threadIdx.x;
    if (t < BS) {
        int b = t;
        int hv = h_index[b * NEG1];
        int all = 1;
        for (int j = 1; j < NEG1; j++) all &= (h_index[b * NEG1 + j] == hv);
        s_isneg[b] = all;
        int h0v = all ? hv : t_index[b * NEG1];
        int r0v = all ? r_index[b * NEG1] : r_index[b * NEG1] + 64;
        s_r0[b] = r0v;
        h0[b] = h0v;
        r0[b] = r0v;
    }
    __syncthreads();
    {
        int b = t >> 5, dd = t & 31;
        query[t] = rel_query[s_r0[b] * DDIM + dd];
    }
    for (int idx = t; idx < BS * NEG1; idx += 256) {
        int b = idx / NEG1;
        tnew[idx] = s_isneg[b] ? t_index[idx] : h_index[idx];
    }
}

__global__ void rel_kernel(const float* __restrict__ rel_query, const float* __restrict__ Wrel,
                           const float* __restrict__ brel, float* __restrict__ rel_all) {
    int idx = blockIdx.x * 256 + threadIdx.x;
    if (idx >= NLAYER * NRELX2 * DDIM) return;
    int i  = idx >> 12;          // / 4096
    int q  = (idx >> 5) & 127;
    int dd = idx & 31;
    float acc = brel[i * DDIM + dd];
    #pragma unroll
    for (int k = 0; k < DDIM; k++)
        acc = fmaf(rel_query[q * DDIM + k], Wrel[i * DDIM * DDIM + k * DDIM + dd], acc);
    rel_all[idx] = acc;
}

// Wg[layer][step][j][dd] = Wlin[layer][k_j(dd)][(dd+step)&31]
__global__ void wg_kernel(const float* __restrict__ Wlin, float* __restrict__ wg) {
    int idx = blockIdx.x * 256 + threadIdx.x;       // NLAYER*32*13*32
    if (idx >= NLAYER * 32 * 13 * 32) return;
    int dd = idx & 31;
    int r  = idx >> 5;
    int j  = r % 13;
    int r2 = r / 13;
    int step  = r2 & 31;
    int layer = r2 >> 5;
    int k;
    if (j == 0) k = dd;
    else { int s = (j - 1) / 3, scl = (j - 1) % 3; k = 32 + (dd * 4 + s) * 3 + scl; }
    int col = (dd + step) & 31;
    wg[idx] = Wlin[(layer * INW + k) * DDIM + col];
}

__global__ void init_x_kernel(float* __restrict__ x, const int* __restrict__ h0,
                              const float* __restrict__ query) {
    int i = blockIdx.x * 256 + threadIdx.x;
    if (i >= NNODE * FEAT) return;
    int n = i >> 8;
    int t = i & 255;
    int b = t >> 5;
    x[i] = (h0[b] == n) ? query[t] : 0.f;
}

// ---------------------------------------------------------------- main layer
// Per block: 10 nodes, ONE group, 7 raw stats/node. GEMM: systolic rotation,
// register-double-buffered weights. __launch_bounds__(256,1): relax the
// allocator so all ~116 live floats sit in ARCH VGPRs (no AGPR split ->
// no v_accvgpr_read per stat use, true occupancy governed by real usage).

#define STATS_COMP(U, NODE) {                                                 \
    int n_ = (NODE);                                                          \
    float bv_ = (h0b == n_) ? q : 0.f;                                        \
    float sum_ = bv_, ssq_ = bv_ * bv_, vmx_ = bv_, vmn_ = bv_;               \
    int e0_ = row_ptr[n_], e1_ = row_ptr[n_ + 1];                             \
    xm##U = x_in[n_ * FEAT + t];                                              \
    int e_ = e0_;                                                             \
    for (; e_ + 3 < e1_; e_ += 4) {                                           \
        int pa_ = csr_pack[e_];                                               \
        int pb_ = csr_pack[e_ + 1];                                           \
        int pc_ = csr_pack[e_ + 2];                                           \
        int pd_ = csr_pack[e_ + 3];                                           \
        float xa_ = x_in[(pa_ >> 16) * FEAT + t];                             \
        float xb_ = x_in[(pb_ >> 16) * FEAT + t];                             \
        float xc_ = x_in[(pc_ >> 16) * FEAT + t];                             \
        float xd_ = x_in[(pd_ >> 16) * FEAT + t];                             \
        float ra_ = s_rel[((pa_ & 0xFFFF) << 5) + dd];                        \
        float rb_ = s_rel[((pb_ & 0xFFFF) << 5) + dd];                        \
        float rc_ = s_rel[((pc_ & 0xFFFF) << 5) + dd];                        \
        float rd_ = s_rel[((pd_ & 0xFFFF) << 5) + dd];                        \
        float ma_ = xa_ * ra_, mb_ = xb_ * rb_;                               \
        float mc_ = xc_ * rc_, md_ = xd_ * rd_;                               \
        sum_ += ((ma_ + mb_) + (mc_ + md_));                                  \
        ssq_ = fmaf(ma_, ma_, ssq_); ssq_ = fmaf(mb_, mb_, ssq_);             \
        ssq_ = fmaf(mc_, mc_, ssq_); ssq_ = fmaf(md_, md_, ssq_);             \
        vmx_ = fmaxf(vmx_, fmaxf(fmaxf(ma_, mb_), fmaxf(mc_, md_)));         \
        vmn_ = fminf(vmn_, fminf(fminf(ma_, mb_), fminf(mc_, md_)));         \
    }                                                                         \
    for (; e_ < e1_; ++e_) {                                                  \
        int p_  = csr_pack[e_];                                               \
        float m_ = x_in[(p_ >> 16) * FEAT + t]                                \
                   * s_rel[((p_ & 0xFFFF) << 5) + dd];                        \
        sum_ += m_; ssq_ = fmaf(m_, m_, ssq_);                                \
        vmx_ = fmaxf(vmx_, m_); vmn_ = fminf(vmn_, m_);                       \
    }                                                                         \
    float dv_ = dinv[n_];                                                     \
    mean##U = sum_ * dv_;                                                     \
    float sq_ = ssq_ * dv_;                                                   \
    mx##U = vmx_; mn##U = vmn_;                                               \
    sd##U = sqrtf(fmaxf(sq_ - mean##U * mean##U, 1e-6f));                     \
    float sv_ = sc[n_];                                                       \
    sv##U = sv_; s2##U = 1.0f / fmaxf(sv_, 0.01f);                            \
}

#define SDECL(U) float xm##U, mean##U, mx##U, mn##U, sd##U, sv##U, s2##U;

#define GSTEP(U) {                                                            \
    float a_ = acc##U;                                                        \
    a_ = fmaf(xm##U, cw0, a_);                                                \
    float t0_ = fmaf(sv##U, cw2,  cw1);  t0_ = fmaf(s2##U, cw3,  t0_);        \
    a_ = fmaf(mean##U, t0_, a_);                                              \
    float t1_ = fmaf(sv##U, cw5,  cw4);  t1_ = fmaf(s2##U, cw6,  t1_);        \
    a_ = fmaf(mx##U,   t1_, a_);                                              \
    float t2_ = fmaf(sv##U, cw8,  cw7);  t2_ = fmaf(s2##U, cw9,  t2_);        \
    a_ = fmaf(mn##U,   t2_, a_);                                              \
    float t3_ = fmaf(sv##U, cw11, cw10); t3_ = fmaf(s2##U, cw12, t3_);        \
    a_ = fmaf(sd##U,   t3_, a_);                                              \
    acc##U = a_;                                                              \
}

#define ROT(U) acc##U = __int_as_float(__builtin_amdgcn_ds_bpermute(          \
                            bperm_addr, __float_as_int(acc##U)));

#define LNSTORE(U, NODE) {                                                    \
    int n_ = (NODE);                                                          \
    float v_ = acc##U;                                                        \
    float s1_ = v_;                                                           \
    s1_ += __shfl_xor(s1_, 16, 32); s1_ += __shfl_xor(s1_, 8, 32);            \
    s1_ += __shfl_xor(s1_, 4, 32);  s1_ += __shfl_xor(s1_, 2, 32);            \
    s1_ += __shfl_xor(s1_, 1, 32);                                            \
    float lm_ = s1_ * (1.0f / 32.0f);                                         \
    float dl_ = v_ - lm_;                                                     \
    float p2_ = dl_ * dl_;                                                    \
    p2_ += __shfl_xor(p2_, 16, 32); p2_ += __shfl_xor(p2_, 8, 32);            \
    p2_ += __shfl_xor(p2_, 4, 32);  p2_ += __shfl_xor(p2_, 2, 32);            \
    p2_ += __shfl_xor(p2_, 1, 32);                                            \
    float var_ = p2_ * (1.0f / 32.0f);                                        \
    float y_ = dl_ / sqrtf(var_ + 1e-5f) * gdd + bdd;                         \
    y_ = fmaxf(y_, 0.0f);                                                     \
    x_out[n_ * FEAT + t] = y_ + xm##U;                                        \
}

__global__ __launch_bounds__(256, 1) void layer_kernel(
    const float* __restrict__ x_in, float* __restrict__ x_out,
    const int* __restrict__ row_ptr, const int* __restrict__ csr_pack,
    const float* __restrict__ rel_i,     // [128][32]
    const float* __restrict__ wg_i,      // [32][13][32]
    const float* __restrict__ blin_i, const float* __restrict__ g_i,
    const float* __restrict__ b_i,
    const float* __restrict__ dinv, const float* __restrict__ sc,
    const int* __restrict__ h0, const float* __restrict__ query) {
    int t  = threadIdx.x;
    int b  = t >> 5, dd = t & 31;
    int lane = t & 63;
    __shared__ float s_rel[NRELX2 * DDIM];   // 16 KB

    for (int k = t; k < NRELX2 * DDIM; k += 256) s_rel[k] = rel_i[k];

    float q   = query[t];
    int   h0b = h0[b];
    float gdd = g_i[dd], bdd = b_i[dd], bl = blin_i[dd];
    // rotate-down-by-1 within each 32-lane half of the wave (pull from lane+1)
    int bperm_addr = ((((lane + 1) & 31) | (lane & 32)) << 2);
    __syncthreads();

    int nbase = blockIdx.x * NPB;
    SDECL(0) SDECL(1) SDECL(2) SDECL(3) SDECL(4)
    SDECL(5) SDECL(6) SDECL(7) SDECL(8) SDECL(9)
    STATS_COMP(0, nbase + 0)
    STATS_COMP(1, nbase + 1)
    STATS_COMP(2, nbase + 2)
    STATS_COMP(3, nbase + 3)
    STATS_COMP(4, nbase + 4)
    STATS_COMP(5, nbase + 5)
    STATS_COMP(6, nbase + 6)
    STATS_COMP(7, nbase + 7)
    STATS_COMP(8, nbase + 8)
    STATS_COMP(9, nbase + 9)

    float acc0 = bl, acc1 = bl, acc2 = bl, acc3 = bl, acc4 = bl;
    float acc5 = bl, acc6 = bl, acc7 = bl, acc8 = bl, acc9 = bl;

    // prologue: load step 0 weights
    const float* wp0 = wg_i + dd;
    float cw0  = wp0[0 * 32],  cw1  = wp0[1 * 32],  cw2  = wp0[2 * 32];
    float cw3  = wp0[3 * 32],  cw4  = wp0[4 * 32],  cw5  = wp0[5 * 32];
    float cw6  = wp0[6 * 32],  cw7  = wp0[7 * 32],  cw8  = wp0[8 * 32];
    float cw9  = wp0[9 * 32],  cw10 = wp0[10 * 32], cw11 = wp0[11 * 32];
    float cw12 = wp0[12 * 32];

    #pragma unroll 1
    for (int i = 0; i < 32; ++i) {
        // prefetch next step's weights (wraps on last iter; values unused)
        const float* wn = wg_i + ((i + 1) & 31) * 416 + dd;
        float nw0  = wn[0 * 32],  nw1  = wn[1 * 32],  nw2  = wn[2 * 32];
        float nw3  = wn[3 * 32],  nw4  = wn[4 * 32],  nw5  = wn[5 * 32];
        float nw6  = wn[6 * 32],  nw7  = wn[7 * 32],  nw8  = wn[8 * 32];
        float nw9  = wn[9 * 32],  nw10 = wn[10 * 32], nw11 = wn[11 * 32];
        float nw12 = wn[12 * 32];

        GSTEP(0) GSTEP(1) GSTEP(2) GSTEP(3) GSTEP(4)
        GSTEP(5) GSTEP(6) GSTEP(7) GSTEP(8) GSTEP(9)
        ROT(0) ROT(1) ROT(2) ROT(3) ROT(4)
        ROT(5) ROT(6) ROT(7) ROT(8) ROT(9)

        cw0 = nw0;  cw1 = nw1;  cw2 = nw2;  cw3 = nw3;  cw4 = nw4;
        cw5 = nw5;  cw6 = nw6;  cw7 = nw7;  cw8 = nw8;  cw9 = nw9;
        cw10 = nw10; cw11 = nw11; cw12 = nw12;
    }
    // 32 rotations = identity: lane dd again holds col dd

    LNSTORE(0, nbase + 0)
    LNSTORE(1, nbase + 1)
    LNSTORE(2, nbase + 2)
    LNSTORE(3, nbase + 3)
    LNSTORE(4, nbase + 4)
    LNSTORE(5, nbase + 5)
    LNSTORE(6, nbase + 6)
    LNSTORE(7, nbase + 7)
    LNSTORE(8, nbase + 8)
    LNSTORE(9, nbase + 9)
}

// ---------------------------------------------------------------- readout
__global__ void score_kernel(const float* __restrict__ x, const int* __restrict__ tnew,
                             const float* __restrict__ query,
                             const float* __restrict__ W1, const float* __restrict__ b1,
                             const float* __restrict__ W2, const float* __restrict__ b2,
                             float* __restrict__ out) {
    int idx = blockIdx.x;         // b*33+j
    int b = idx / NEG1;
    int k = threadIdx.x;          // 0..63
    __shared__ float v[64];
    int tnode = tnew[idx];
    if (k < 32) v[k] = x[tnode * FEAT + b * DDIM + k];
    else        v[k] = query[b * DDIM + (k - 32)];
    __syncthreads();
    float acc = b1[k];
    #pragma unroll
    for (int l = 0; l < 64; l++) acc = fmaf(v[l], W1[l * 64 + k], acc);
    acc = fmaxf(acc, 0.f);
    float p = acc * W2[k];
    #pragma unroll
    for (int m = 32; m >= 1; m >>= 1) p += __shfl_xor(p, m);
    if (k == 0) out[idx] = p + b2[0];
}

// ---------------------------------------------------------------- launch
extern "C" void kernel_launch(void* const* d_in, const int* in_sizes, int n_in,
                              void* d_out, int out_size, void* d_ws, size_t ws_size,
                              hipStream_t stream) {
    const int* edge_src  = (const int*)d_in[0];
    const int* edge_dst  = (const int*)d_in[1];
    const int* edge_type = (const int*)d_in[2];
    const int* h_index   = (const int*)d_in[3];
    const int* t_index   = (const int*)d_in[4];
    const int* r_index   = (const int*)d_in[5];
    const float* rel_query = (const float*)d_in[7];
    const float* Wrel    = (const float*)d_in[8];
    const float* brel    = (const float*)d_in[9];
    const float* Wlin    = (const float*)d_in[10];
    const float* blin    = (const float*)d_in[11];
    const float* ln_g    = (const float*)d_in[12];
    const float* ln_b    = (const float*)d_in[13];
    const float* W1      = (const float*)d_in[14];
    const float* b1      = (const float*)d_in[15];
    const float* W2      = (const float*)d_in[16];
    const float* b2      = (const float*)d_in[17];

    const int N  = NNODE;
    const int E  = in_sizes[0];
    const int E2 = 2 * E;

    char* p = (char*)d_ws;
    auto carve = [&](size_t bytes) {
        void* r = (void*)p;
        p += (bytes + 255) & ~(size_t)255;
        return r;
    };
    float* x0      = (float*)carve((size_t)N * FEAT * 4);
    float* x1      = (float*)carve((size_t)N * FEAT * 4);
    int*   cnt     = (int*)carve((size_t)N * 4);
    int*   row_ptr = (int*)carve((size_t)(N + 1) * 4);
    int*   cursor  = (int*)carve((size_t)N * 4);
    int*   csr_pack= (int*)carve((size_t)E2 * 4);
    float* dinv    = (float*)carve((size_t)N * 4);
    float* logdeg  = (float*)carve((size_t)N * 4);
    float* scn     = (float*)carve((size_t)N * 4);
    float* meanp   = (float*)carve(16);
    float* rel_all = (float*)carve((size_t)NLAYER * NRELX2 * DDIM * 4);
    float* wg      = (float*)carve((size_t)NLAYER * 32 * 13 * 32 * 4);
    int*   h0      = (int*)carve(BS * 4);
    int*   r0      = (int*)carve(BS * 4);
    float* query   = (float*)carve(BS * DDIM * 4);
    int*   tnew    = (int*)carve(BS * NEG1 * 4);

    hipMemsetAsync(cnt, 0, (size_t)N * 4, stream);
    hipMemsetAsync(cursor, 0, (size_t)N * 4, stream);

    int eb = (E2 + 255) / 256;
    count_kernel<<<eb, 256, 0, stream>>>(edge_src, edge_dst, cnt, E);
    scan_kernel<<<1, 1024, 0, stream>>>(cnt, row_ptr, N);
    fill_kernel<<<eb, 256, 0, stream>>>(edge_src, edge_dst, edge_type, row_ptr,
                                        cursor, csr_pack, E);
    deg_kernel<<<(N + 255) / 256, 256, 0, stream>>>(cnt, dinv, logdeg, N);
    mean_kernel<<<1, 256, 0, stream>>>(logdeg, meanp, N);
    sc_kernel<<<(N + 255) / 256, 256, 0, stream>>>(logdeg, meanp, scn, N);
    prep_kernel<<<1, 256, 0, stream>>>(h_index, t_index, r_index, rel_query,
                                       h0, r0, query, tnew);
    rel_kernel<<<(NLAYER * NRELX2 * DDIM + 255) / 256, 256, 0, stream>>>(
        rel_query, Wrel, brel, rel_all);
    wg_kernel<<<(NLAYER * 32 * 13 * 32 + 255) / 256, 256, 0, stream>>>(Wlin, wg);
    init_x_kernel<<<(N * FEAT + 255) / 256, 256, 0, stream>>>(x0, h0, query);

    float* xin = x0;
    float* xout = x1;
    for (int i = 0; i < NLAYER; ++i) {
        layer_kernel<<<N / NPB, 256, 0, stream>>>(
            xin, xout, row_ptr, csr_pack,
            rel_all + (size_t)i * NRELX2 * DDIM,
            wg + (size_t)i * 32 * 13 * 32,
            blin + (size_t)i * DDIM,
            ln_g + (size_t)i * DDIM,
            ln_b + (size_t)i * DDIM,
            dinv, scn, h0, query);
        float* tmp = xin; xin = xout; xout = tmp;
    }

    score_kernel<<<BS * NEG1, 64, 0, stream>>>(xin, tnew, query, W1, b1, W2, b2,
                                               (float*)d_out);
}